// Round 4
// baseline (87.736 us; speedup 1.0000x reference)
//
#include <hip/hip_runtime.h>
#include <math.h>

// Problem constants (from reference): x[B][L][D] fp32
#define B 8
#define L 4096
#define D 512
#define LC 64               // chunk length
#define CK (L / LC)         // 64 chunks
#define HD (D / 2)          // 2 channels per thread
#define BLD ((size_t)B * L * D)

typedef float v2f __attribute__((ext_vector_type(2)));
typedef float v4f __attribute__((ext_vector_type(4)));

// ws layout (floats):
//   phz  [D][2]            offset 0
//   pi   [D][2]            offset 2*D
//   Ptab [CK][D][2]        offset 4*D          (Ptab[k][d] = phazor[d]^(k*LC), fp64-exact)
//   le   [B][CK][D][2]     offset 4*D + 2*CK*D (chunk-local scan ends)
#define WS_PHZ   0
#define WS_PI    (2 * D)
#define WS_PTAB  (4 * D)
#define WS_LE    (4 * D + 2 * CK * D)
#define WS_FLOATS (WS_LE + 2 * B * CK * D)

__global__ __launch_bounds__(256) void setup_k(const float* __restrict__ pinit,
                                               const float* __restrict__ pparam,
                                               float* __restrict__ ws) {
    int d = blockIdx.x * blockDim.x + threadIdx.x;
    if (d >= D) return;
    float a = pparam[d * 2 + 0];
    float bb = pparam[d * 2 + 1];
    double r2 = (double)a * (double)a + (double)bb * (double)bb;
    double th = atan2((double)bb, (double)a);
    double mag = exp(-r2);
    ws[WS_PHZ + d * 2 + 0] = (float)(mag * cos(th));
    ws[WS_PHZ + d * 2 + 1] = (float)(mag * sin(th));
    ws[WS_PI + d * 2 + 0] = pinit[d * 2 + 0];
    ws[WS_PI + d * 2 + 1] = pinit[d * 2 + 1];
    float* P = ws + WS_PTAB;
    for (int c = 0; c < CK; ++c) {
        double t = (double)(c * LC);
        double e = exp(-t * r2);
        double ang = t * th;
        P[(c * D + d) * 2 + 0] = (float)(e * cos(ang));
        P[(c * D + d) * 2 + 1] = (float)(e * sin(ang));
    }
}

// Pass 1: chunk-local scan (zero carry-in) for 2 adjacent channels per thread.
__global__ __launch_bounds__(256) void pass1_k(const float* __restrict__ x,
                                               const float* __restrict__ ws,
                                               float* __restrict__ le) {
    int idx = blockIdx.x * blockDim.x + threadIdx.x;   // b*CK*HD + c*HD + h
    int h = idx % HD;
    int c = (idx / HD) % CK;
    int b = idx / (HD * CK);
    int d0 = h * 2;
    v4f ph = *(const v4f*)(ws + WS_PHZ + d0 * 2);   // pr0,pi0,pr1,pi1
    float ur0 = 0.f, ui0 = 0.f, ur1 = 0.f, ui1 = 0.f;
    const float* xp = x + ((size_t)b * L + (size_t)c * LC) * D + d0;
#pragma unroll 8
    for (int i = 0; i < LC; ++i) {
        v2f xv = *(const v2f*)(xp + (size_t)i * D);
        float nr0 = fmaf(ph.x, ur0, fmaf(-ph.y, ui0, xv.x));
        float ni0 = fmaf(ph.x, ui0, ph.y * ur0);
        float nr1 = fmaf(ph.z, ur1, fmaf(-ph.w, ui1, xv.y));
        float ni1 = fmaf(ph.z, ui1, ph.w * ur1);
        ur0 = nr0; ui0 = ni0; ur1 = nr1; ui1 = ni1;
    }
    v4f lv; lv.x = ur0; lv.y = ui0; lv.z = ur1; lv.w = ui1;
    *(v4f*)(le + ((size_t)(b * CK + c) * D + d0) * 2) = lv;
}

// Pass 2: rebuild carry-in from previous chunk ends (exact power table),
// re-scan the chunk, write outputs.
// MODE 0: out = [real plane][real plane]   (harness cast complex64 -> float32)
// MODE 1: out = [real plane][interleaved (re,im) plane]
template <int MODE>
__global__ __launch_bounds__(256) void pass2_k(const float* __restrict__ x,
                                               const float* __restrict__ hr,
                                               const float* __restrict__ hi,
                                               const float* __restrict__ ws,
                                               const float* __restrict__ le,
                                               float* __restrict__ out) {
    int idx = blockIdx.x * blockDim.x + threadIdx.x;   // b*CK*HD + c*HD + h
    int h = idx % HD;
    int c = (idx / HD) % CK;      // uniform within a block (HD == blockDim)
    int b = idx / (HD * CK);
    int d0 = h * 2;

    v4f ph = *(const v4f*)(ws + WS_PHZ + d0 * 2);   // pr0,pi0,pr1,pi1
    v4f q  = *(const v4f*)(ws + WS_PI + d0 * 2);    // qr0,qi0,qr1,qi1
    const float* P = ws + WS_PTAB;

    // carry-in W[c] = sum_{j<c} phazor^{(c-1-j)*LC} * le[b][j][d]
    float ur0 = 0.f, ui0 = 0.f, ur1 = 0.f, ui1 = 0.f;
    for (int j = 0; j < c; ++j) {
        int k = c - 1 - j;
        v4f Pk = *(const v4f*)(P + ((size_t)k * D + d0) * 2);
        v4f lv = *(const v4f*)(le + ((size_t)(b * CK + j) * D + d0) * 2);
        ur0 = fmaf(Pk.x, lv.x, fmaf(-Pk.y, lv.y, ur0));
        ui0 = fmaf(Pk.x, lv.y, fmaf(Pk.y, lv.x, ui0));
        ur1 = fmaf(Pk.z, lv.z, fmaf(-Pk.w, lv.w, ur1));
        ui1 = fmaf(Pk.z, lv.w, fmaf(Pk.w, lv.z, ui1));
    }

    // pw = phazor^(c*LC + 1) = Ptab[c] * phazor
    v4f Pc = *(const v4f*)(P + ((size_t)c * D + d0) * 2);
    float pwr0 = Pc.x * ph.x - Pc.y * ph.y;
    float pwi0 = fmaf(Pc.x, ph.y, Pc.y * ph.x);
    float pwr1 = Pc.z * ph.z - Pc.w * ph.w;
    float pwi1 = fmaf(Pc.z, ph.w, Pc.w * ph.z);

    v2f hre = *(const v2f*)(hr + (size_t)b * D + d0);
    v2f him = *(const v2f*)(hi + (size_t)b * D + d0);

    const float* xp = x + ((size_t)b * L + (size_t)c * LC) * D + d0;
    float* outr = out + ((size_t)b * L + (size_t)c * LC) * D + d0;
    float* outr2 = outr + BLD;                                  // MODE 0 second plane
    float* outc = out + BLD + (((size_t)b * L + (size_t)c * LC) * D + d0) * 2;

#pragma unroll 4
    for (int i = 0; i < LC; ++i) {
        v2f xv = *(const v2f*)(xp + (size_t)i * D);
        float nr0 = fmaf(ph.x, ur0, fmaf(-ph.y, ui0, xv.x));
        float ni0 = fmaf(ph.x, ui0, ph.y * ur0);
        float nr1 = fmaf(ph.z, ur1, fmaf(-ph.w, ui1, xv.y));
        float ni1 = fmaf(ph.z, ui1, ph.w * ur1);
        ur0 = nr0; ui0 = ni0; ur1 = nr1; ui1 = ni1;
        // val = pi*u + hidden*pw
        float vr0 = fmaf(q.x, ur0, fmaf(-q.y, ui0, fmaf(hre.x, pwr0, -him.x * pwi0)));
        float vi0 = fmaf(q.x, ui0, fmaf(q.y, ur0, fmaf(hre.x, pwi0, him.x * pwr0)));
        float vr1 = fmaf(q.z, ur1, fmaf(-q.w, ui1, fmaf(hre.y, pwr1, -him.y * pwi1)));
        float vi1 = fmaf(q.z, ui1, fmaf(q.w, ur1, fmaf(hre.y, pwi1, him.y * pwr1)));
        v2f vv; vv.x = vr0; vv.y = vr1;
        __builtin_nontemporal_store(vv, (v2f*)(outr + (size_t)i * D));
        if (MODE == 0) {
            __builtin_nontemporal_store(vv, (v2f*)(outr2 + (size_t)i * D));
        } else {
            v4f vc; vc.x = vr0; vc.y = vi0; vc.z = vr1; vc.w = vi1;
            __builtin_nontemporal_store(vc, (v4f*)(outc + (size_t)i * D * 2));
        }
        // pw *= phazor
        float tr0 = fmaf(pwr0, ph.x, -pwi0 * ph.y);
        float ti0 = fmaf(pwr0, ph.y, pwi0 * ph.x);
        float tr1 = fmaf(pwr1, ph.z, -pwi1 * ph.w);
        float ti1 = fmaf(pwr1, ph.w, pwi1 * ph.z);
        pwr0 = tr0; pwi0 = ti0; pwr1 = tr1; pwi1 = ti1;
    }
}

// Fallback (no scratch needed): one thread per (b,d), full-L scan. Used only
// if ws_size is too small for the fast path.
template <int MODE>
__global__ __launch_bounds__(256) void fallback_k(const float* __restrict__ x,
                                                  const float* __restrict__ hr,
                                                  const float* __restrict__ hi,
                                                  const float* __restrict__ pinit,
                                                  const float* __restrict__ pparam,
                                                  float* __restrict__ out) {
    int idx = blockIdx.x * blockDim.x + threadIdx.x;   // b*D + d
    if (idx >= B * D) return;
    int d = idx % D;
    int b = idx / D;
    float a = pparam[d * 2 + 0];
    float bb = pparam[d * 2 + 1];
    double r2 = (double)a * (double)a + (double)bb * (double)bb;
    double th = atan2((double)bb, (double)a);
    double mag = exp(-r2);
    float pr = (float)(mag * cos(th));
    float pim = (float)(mag * sin(th));
    float qr = pinit[d * 2 + 0];
    float qi = pinit[d * 2 + 1];
    float hre = hr[b * D + d];
    float him = hi[b * D + d];
    float ur = 0.f, ui = 0.f;
    float pwr = pr, pwi = pim;                     // phazor^(t+1), t=0
    const float* xp = x + (size_t)b * L * D + d;
    float* outr = out + (size_t)b * L * D + d;
    float* outr2 = outr + BLD;
    float* outc = out + BLD + ((size_t)b * L * D + d) * 2;
    for (int t = 0; t < L; ++t) {
        float xv = xp[(size_t)t * D];
        float nr = fmaf(pr, ur, fmaf(-pim, ui, xv));
        float ni = fmaf(pr, ui, pim * ur);
        ur = nr; ui = ni;
        float vr = fmaf(qr, ur, fmaf(-qi, ui, fmaf(hre, pwr, -him * pwi)));
        float vi = fmaf(qr, ui, fmaf(qi, ur, fmaf(hre, pwi, him * pwr)));
        outr[(size_t)t * D] = vr;
        if (MODE == 0) {
            outr2[(size_t)t * D] = vr;
        } else {
            v2f vc; vc.x = vr; vc.y = vi;
            *(v2f*)(outc + (size_t)t * D * 2) = vc;
        }
        float tr = fmaf(pwr, pr, -pwi * pim);
        float ti = fmaf(pwr, pim, pwi * pr);
        pwr = tr; pwi = ti;
    }
}

extern "C" void kernel_launch(void* const* d_in, const int* in_sizes, int n_in,
                              void* d_out, int out_size, void* d_ws, size_t ws_size,
                              hipStream_t stream) {
    const float* x = (const float*)d_in[0];
    const float* hreal = (const float*)d_in[1];
    const float* himag = (const float*)d_in[2];
    const float* pinit = (const float*)d_in[3];
    const float* pparam = (const float*)d_in[4];
    float* ws = (float*)d_ws;
    float* out = (float*)d_out;

    const int mode = (out_size >= (int)(3 * BLD)) ? 1 : 0;
    const bool fast = ws_size >= (size_t)WS_FLOATS * sizeof(float);

    if (fast) {
        float* le = ws + WS_LE;
        setup_k<<<(D + 255) / 256, 256, 0, stream>>>(pinit, pparam, ws);
        int n = B * CK * HD;                      // 131072 threads
        pass1_k<<<n / 256, 256, 0, stream>>>(x, ws, le);
        if (mode == 0)
            pass2_k<0><<<n / 256, 256, 0, stream>>>(x, hreal, himag, ws, le, out);
        else
            pass2_k<1><<<n / 256, 256, 0, stream>>>(x, hreal, himag, ws, le, out);
    } else {
        int n = B * D;                            // 4096 threads
        if (mode == 0)
            fallback_k<0><<<(n + 255) / 256, 256, 0, stream>>>(x, hreal, himag, pinit, pparam, out);
        else
            fallback_k<1><<<(n + 255) / 256, 256, 0, stream>>>(x, hreal, himag, pinit, pparam, out);
    }
}

// Round 5
// 58.513 us; speedup vs baseline: 1.4994x; 1.4994x over previous
//
#include <hip/hip_runtime.h>
#include <math.h>

// Problem constants (from reference): x[B][L][D] fp32
#define B 8
#define L 4096
#define D 512
#define LC 64               // chunk length
#define CK (L / LC)         // 64 chunks
#define BLD ((size_t)B * L * D)

typedef float v2f __attribute__((ext_vector_type(2)));

// ws layout (floats):
//   phz  [D][2]            offset 0
//   pi   [D][2]            offset 2*D
//   Ptab [CK][D][2]        offset 4*D          (Ptab[c][d] = phazor[d]^(c*LC), fp64-exact)
//   le   [B][CK][D][2]     offset 4*D + 2*CK*D (chunk-local scan ends)
#define WS_PHZ   0
#define WS_PI    (2 * D)
#define WS_PTAB  (4 * D)
#define WS_LE    (4 * D + 2 * CK * D)
#define WS_FLOATS (WS_LE + 2 * B * CK * D)   // ~592K floats = 2.37 MB (proven available, round 4)

// One thread per (c,d): Ptab[c][d] = phazor^(c*LC) via fp64 complex binary
// exponentiation. No trig: exp(i*angle(z)) = (a+ib)/|z| exactly.
__global__ __launch_bounds__(256) void setup_k(const float* __restrict__ pinit,
                                               const float* __restrict__ pparam,
                                               float* __restrict__ ws) {
    int idx = blockIdx.x * blockDim.x + threadIdx.x;   // c*D + d
    if (idx >= CK * D) return;
    int d = idx % D;
    int c = idx / D;
    double a = (double)pparam[d * 2 + 0];
    double bb = (double)pparam[d * 2 + 1];
    double r2 = a * a + bb * bb;
    double inv = 1.0 / sqrt(r2);
    double mag = exp(-r2);
    double phr = mag * a * inv;                        // phazor (fp64)
    double phi = mag * bb * inv;
    // res = phazor^(c*LC)
    double rr = 1.0, ri = 0.0;
    double br = phr, bi = phi;
    int n = c * LC;
    while (n) {
        if (n & 1) {
            double tr = rr * br - ri * bi;
            double ti = rr * bi + ri * br;
            rr = tr; ri = ti;
        }
        double sr = br * br - bi * bi;
        double si = 2.0 * br * bi;
        br = sr; bi = si;
        n >>= 1;
    }
    ws[WS_PTAB + (c * D + d) * 2 + 0] = (float)rr;
    ws[WS_PTAB + (c * D + d) * 2 + 1] = (float)ri;
    if (c == 0) {
        ws[WS_PHZ + d * 2 + 0] = (float)phr;
        ws[WS_PHZ + d * 2 + 1] = (float)phi;
        ws[WS_PI + d * 2 + 0] = pinit[d * 2 + 0];
        ws[WS_PI + d * 2 + 1] = pinit[d * 2 + 1];
    }
}

// Pass 1: chunk-local scan with zero carry-in; store final state per (b,c,d).
__global__ __launch_bounds__(256) void pass1_k(const float* __restrict__ x,
                                               const float* __restrict__ ws,
                                               float* __restrict__ le) {
    int idx = blockIdx.x * blockDim.x + threadIdx.x;   // b*CK*D + c*D + d
    int d = idx % D;
    int c = (idx / D) % CK;
    int b = idx / (D * CK);
    v2f ph = *(const v2f*)(ws + WS_PHZ + d * 2);
    float ur = 0.f, ui = 0.f;
    const float* xp = x + ((size_t)b * L + (size_t)c * LC) * D + d;
#pragma unroll 8
    for (int i = 0; i < LC; ++i) {
        float xv = xp[(size_t)i * D];
        float nr = fmaf(ph.x, ur, fmaf(-ph.y, ui, xv));
        float ni = fmaf(ph.x, ui, ph.y * ur);
        ur = nr;
        ui = ni;
    }
    v2f lv; lv.x = ur; lv.y = ui;
    *(v2f*)(le + (size_t)idx * 2) = lv;
}

// Pass 2: rebuild carry-in from previous chunk ends (exact power table),
// re-scan the chunk, write outputs.
// MODE 0: out = [real plane][real plane]   (harness cast complex64 -> float32)
// MODE 1: out = [real plane][interleaved (re,im) plane]
template <int MODE>
__global__ __launch_bounds__(256) void pass2_k(const float* __restrict__ x,
                                               const float* __restrict__ hr,
                                               const float* __restrict__ hi,
                                               const float* __restrict__ ws,
                                               const float* __restrict__ le,
                                               float* __restrict__ out) {
    int idx = blockIdx.x * blockDim.x + threadIdx.x;   // b*CK*D + c*D + d
    int d = idx % D;
    int c = (idx / D) % CK;       // uniform within a block
    int b = idx / (D * CK);

    v2f ph = *(const v2f*)(ws + WS_PHZ + d * 2);
    v2f q  = *(const v2f*)(ws + WS_PI + d * 2);
    const float* P = ws + WS_PTAB;

    // carry-in W[c] = sum_{j<c} phazor^{(c-1-j)*LC} * le[b][j][d]
    float ur = 0.f, ui = 0.f;
    for (int j = 0; j < c; ++j) {
        int k = c - 1 - j;
        v2f Pk = *(const v2f*)(P + ((size_t)k * D + d) * 2);
        v2f lv = *(const v2f*)(le + (((size_t)b * CK + j) * D + d) * 2);
        ur = fmaf(Pk.x, lv.x, fmaf(-Pk.y, lv.y, ur));
        ui = fmaf(Pk.x, lv.y, fmaf(Pk.y, lv.x, ui));
    }

    // pw = phazor^(c*LC + 1) = Ptab[c] * phazor
    v2f Pc = *(const v2f*)(P + ((size_t)c * D + d) * 2);
    float pwr = Pc.x * ph.x - Pc.y * ph.y;
    float pwi = fmaf(Pc.x, ph.y, Pc.y * ph.x);

    float hre = hr[(size_t)b * D + d];
    float him = hi[(size_t)b * D + d];

    const float* xp = x + ((size_t)b * L + (size_t)c * LC) * D + d;
    float* outr = out + ((size_t)b * L + (size_t)c * LC) * D + d;
    float* outr2 = outr + BLD;                                  // MODE 0 second plane
    float* outc = out + BLD + (((size_t)b * L + (size_t)c * LC) * D + d) * 2;

#pragma unroll 4
    for (int i = 0; i < LC; ++i) {
        float xv = xp[(size_t)i * D];
        float nr = fmaf(ph.x, ur, fmaf(-ph.y, ui, xv));
        float ni = fmaf(ph.x, ui, ph.y * ur);
        ur = nr;
        ui = ni;
        // val = pi*u + hidden*pw
        float vr = fmaf(q.x, ur, fmaf(-q.y, ui, fmaf(hre, pwr, -him * pwi)));
        float vi = fmaf(q.x, ui, fmaf(q.y, ur, fmaf(hre, pwi, him * pwr)));
        outr[(size_t)i * D] = vr;
        if (MODE == 0) {
            outr2[(size_t)i * D] = vr;
        } else {
            v2f vc; vc.x = vr; vc.y = vi;
            *(v2f*)(outc + (size_t)i * D * 2) = vc;
        }
        // pw *= phazor
        float tr = fmaf(pwr, ph.x, -pwi * ph.y);
        float ti = fmaf(pwr, ph.y, pwi * ph.x);
        pwr = tr;
        pwi = ti;
    }
}

// Fallback (no scratch needed): one thread per (b,d), full-L scan. Used only
// if ws_size is too small for the fast path.
template <int MODE>
__global__ __launch_bounds__(256) void fallback_k(const float* __restrict__ x,
                                                  const float* __restrict__ hr,
                                                  const float* __restrict__ hi,
                                                  const float* __restrict__ pinit,
                                                  const float* __restrict__ pparam,
                                                  float* __restrict__ out) {
    int idx = blockIdx.x * blockDim.x + threadIdx.x;   // b*D + d
    if (idx >= B * D) return;
    int d = idx % D;
    int b = idx / D;
    double a = (double)pparam[d * 2 + 0];
    double bb = (double)pparam[d * 2 + 1];
    double r2 = a * a + bb * bb;
    double inv = 1.0 / sqrt(r2);
    double mag = exp(-r2);
    float pr = (float)(mag * a * inv);
    float pim = (float)(mag * bb * inv);
    float qr = pinit[d * 2 + 0];
    float qi = pinit[d * 2 + 1];
    float hre = hr[(size_t)b * D + d];
    float him = hi[(size_t)b * D + d];
    float ur = 0.f, ui = 0.f;
    float pwr = pr, pwi = pim;                     // phazor^(t+1), t=0
    const float* xp = x + (size_t)b * L * D + d;
    float* outr = out + (size_t)b * L * D + d;
    float* outr2 = outr + BLD;
    float* outc = out + BLD + ((size_t)b * L * D + d) * 2;
    for (int t = 0; t < L; ++t) {
        float xv = xp[(size_t)t * D];
        float nr = fmaf(pr, ur, fmaf(-pim, ui, xv));
        float ni = fmaf(pr, ui, pim * ur);
        ur = nr; ui = ni;
        float vr = fmaf(qr, ur, fmaf(-qi, ui, fmaf(hre, pwr, -him * pwi)));
        float vi = fmaf(qr, ui, fmaf(qi, ur, fmaf(hre, pwi, him * pwr)));
        outr[(size_t)t * D] = vr;
        if (MODE == 0) {
            outr2[(size_t)t * D] = vr;
        } else {
            v2f vc; vc.x = vr; vc.y = vi;
            *(v2f*)(outc + (size_t)t * D * 2) = vc;
        }
        float tr = fmaf(pwr, pr, -pwi * pim);
        float ti = fmaf(pwr, pim, pwi * pr);
        pwr = tr; pwi = ti;
    }
}

extern "C" void kernel_launch(void* const* d_in, const int* in_sizes, int n_in,
                              void* d_out, int out_size, void* d_ws, size_t ws_size,
                              hipStream_t stream) {
    const float* x = (const float*)d_in[0];
    const float* hreal = (const float*)d_in[1];
    const float* himag = (const float*)d_in[2];
    const float* pinit = (const float*)d_in[3];
    const float* pparam = (const float*)d_in[4];
    float* ws = (float*)d_ws;
    float* out = (float*)d_out;

    const int mode = (out_size >= (int)(3 * BLD)) ? 1 : 0;
    const bool fast = ws_size >= (size_t)WS_FLOATS * sizeof(float);

    if (fast) {
        float* le = ws + WS_LE;
        setup_k<<<(CK * D) / 256, 256, 0, stream>>>(pinit, pparam, ws);
        int n = B * CK * D;                       // 262144 threads -> 4 waves/SIMD
        pass1_k<<<n / 256, 256, 0, stream>>>(x, ws, le);
        if (mode == 0)
            pass2_k<0><<<n / 256, 256, 0, stream>>>(x, hreal, himag, ws, le, out);
        else
            pass2_k<1><<<n / 256, 256, 0, stream>>>(x, hreal, himag, ws, le, out);
    } else {
        int n = B * D;                            // 4096 threads
        if (mode == 0)
            fallback_k<0><<<(n + 255) / 256, 256, 0, stream>>>(x, hreal, himag, pinit, pparam, out);
        else
            fallback_k<1><<<(n + 255) / 256, 256, 0, stream>>>(x, hreal, himag, pinit, pparam, out);
    }
}

// Round 6
// 54.094 us; speedup vs baseline: 1.6219x; 1.0817x over previous
//
#include <hip/hip_runtime.h>
#include <math.h>

// Problem constants (from reference): x[B][L][D] fp32
#define B 8
#define L 4096
#define D 512
#define LC 64               // chunk length
#define CK (L / LC)         // 64 chunks
#define BLD ((size_t)B * L * D)

typedef float v2f __attribute__((ext_vector_type(2)));

// ws layout (floats): le [B][CK][D][2]  (chunk-local scan end states)
#define WS_FLOATS (2 * B * CK * D)           // 2 MiB

// phazor = exp(-|z|^2) * z/|z|   (no trig needed)
__device__ __forceinline__ v2f phazor_of(const float* __restrict__ pparam, int d) {
    float a = pparam[d * 2 + 0];
    float bb = pparam[d * 2 + 1];
    float r2 = fmaf(a, a, bb * bb);
    float inv = rsqrtf(r2);
    // one Newton refinement of rsqrt for safety
    inv = inv * fmaf(-0.5f * r2 * inv, inv, 1.5f);
    float mag = __expf(-r2);
    v2f p; p.x = mag * a * inv; p.y = mag * bb * inv;
    return p;
}

// Pass 1: chunk-local scan with zero carry-in; store final state per (b,c,d).
__global__ __launch_bounds__(256) void pass1_k(const float* __restrict__ x,
                                               const float* __restrict__ pparam,
                                               float* __restrict__ le) {
    int idx = blockIdx.x * blockDim.x + threadIdx.x;   // b*CK*D + c*D + d
    int d = idx % D;
    int c = (idx / D) % CK;
    int b = idx / (D * CK);
    v2f ph = phazor_of(pparam, d);
    float ur = 0.f, ui = 0.f;
    const float* xp = x + ((size_t)b * L + (size_t)c * LC) * D + d;
#pragma unroll 8
    for (int i = 0; i < LC; ++i) {
        float xv = xp[(size_t)i * D];
        float nr = fmaf(ph.x, ur, fmaf(-ph.y, ui, xv));
        float ni = fmaf(ph.x, ui, ph.y * ur);
        ur = nr;
        ui = ni;
    }
    v2f lv; lv.x = ur; lv.y = ui;
    *(v2f*)(le + (size_t)idx * 2) = lv;
}

// Pass 2: rebuild carry-in by Horner over previous chunk ends (only needs
// P64 = phazor^LC), re-scan the chunk, write outputs.
// MODE 0: out = [real plane][real plane]   (harness cast complex64 -> float32)
// MODE 1: out = [real plane][interleaved (re,im) plane]
template <int MODE>
__global__ __launch_bounds__(256) void pass2_k(const float* __restrict__ x,
                                               const float* __restrict__ hr,
                                               const float* __restrict__ hi,
                                               const float* __restrict__ pinit,
                                               const float* __restrict__ pparam,
                                               const float* __restrict__ le,
                                               float* __restrict__ out) {
    int idx = blockIdx.x * blockDim.x + threadIdx.x;   // b*CK*D + c*D + d
    int d = idx % D;
    int c = (idx / D) % CK;       // uniform within a block
    int b = idx / (D * CK);

    v2f ph = phazor_of(pparam, d);
    v2f q;  q.x = pinit[d * 2 + 0]; q.y = pinit[d * 2 + 1];

    // P64 = phazor^LC via 6 complex squarings
    float br = ph.x, bi = ph.y;
#pragma unroll
    for (int s = 0; s < 6; ++s) {
        float sr = fmaf(br, br, -bi * bi);
        float si = 2.f * br * bi;
        br = sr; bi = si;
    }

    // carry-in W[c] = sum_{j<c} P64^{c-1-j} * le[b][j][d]  (Horner, ascending j)
    float ur = 0.f, ui = 0.f;
    const float* lp = le + (((size_t)b * CK) * D + d) * 2;
    for (int j = 0; j < c; ++j) {
        v2f lv = *(const v2f*)(lp + (size_t)j * D * 2);
        float wr = fmaf(ur, br, fmaf(-ui, bi, lv.x));
        float wi = fmaf(ur, bi, fmaf(ui, br, lv.y));
        ur = wr; ui = wi;
    }

    // pw = phazor^(c*LC + 1) = P64^c * phazor  (binary exp over 6 bits of c)
    float pwr = ph.x, pwi = ph.y;
    {
        float er = br, ei = bi;     // P64^(2^s)
        int n = c;
#pragma unroll
        for (int s = 0; s < 6; ++s) {
            if (n & 1) {
                float tr = fmaf(pwr, er, -pwi * ei);
                float ti = fmaf(pwr, ei, pwi * er);
                pwr = tr; pwi = ti;
            }
            float sr = fmaf(er, er, -ei * ei);
            float si = 2.f * er * ei;
            er = sr; ei = si;
            n >>= 1;
        }
    }

    float hre = hr[(size_t)b * D + d];
    float him = hi[(size_t)b * D + d];

    const float* xp = x + ((size_t)b * L + (size_t)c * LC) * D + d;
    float* outr = out + ((size_t)b * L + (size_t)c * LC) * D + d;
    float* outr2 = outr + BLD;                                  // MODE 0 second plane
    float* outc = out + BLD + (((size_t)b * L + (size_t)c * LC) * D + d) * 2;

#pragma unroll 4
    for (int i = 0; i < LC; ++i) {
        float xv = xp[(size_t)i * D];
        float nr = fmaf(ph.x, ur, fmaf(-ph.y, ui, xv));
        float ni = fmaf(ph.x, ui, ph.y * ur);
        ur = nr;
        ui = ni;
        // val = pi*u + hidden*pw
        float vr = fmaf(q.x, ur, fmaf(-q.y, ui, fmaf(hre, pwr, -him * pwi)));
        float vi = fmaf(q.x, ui, fmaf(q.y, ur, fmaf(hre, pwi, him * pwr)));
        outr[(size_t)i * D] = vr;
        if (MODE == 0) {
            outr2[(size_t)i * D] = vr;
        } else {
            v2f vc; vc.x = vr; vc.y = vi;
            *(v2f*)(outc + (size_t)i * D * 2) = vc;
        }
        // pw *= phazor
        float tr = fmaf(pwr, ph.x, -pwi * ph.y);
        float ti = fmaf(pwr, ph.y, pwi * ph.x);
        pwr = tr;
        pwi = ti;
    }
}

// Fallback (no scratch needed): one thread per (b,d), full-L scan. Used only
// if ws_size is too small for the fast path.
template <int MODE>
__global__ __launch_bounds__(256) void fallback_k(const float* __restrict__ x,
                                                  const float* __restrict__ hr,
                                                  const float* __restrict__ hi,
                                                  const float* __restrict__ pinit,
                                                  const float* __restrict__ pparam,
                                                  float* __restrict__ out) {
    int idx = blockIdx.x * blockDim.x + threadIdx.x;   // b*D + d
    if (idx >= B * D) return;
    int d = idx % D;
    int b = idx / D;
    v2f ph = phazor_of(pparam, d);
    float qr = pinit[d * 2 + 0];
    float qi = pinit[d * 2 + 1];
    float hre = hr[(size_t)b * D + d];
    float him = hi[(size_t)b * D + d];
    float ur = 0.f, ui = 0.f;
    float pwr = ph.x, pwi = ph.y;                  // phazor^(t+1), t=0
    const float* xp = x + (size_t)b * L * D + d;
    float* outr = out + (size_t)b * L * D + d;
    float* outr2 = outr + BLD;
    float* outc = out + BLD + ((size_t)b * L * D + d) * 2;
    for (int t = 0; t < L; ++t) {
        float xv = xp[(size_t)t * D];
        float nr = fmaf(ph.x, ur, fmaf(-ph.y, ui, xv));
        float ni = fmaf(ph.x, ui, ph.y * ur);
        ur = nr; ui = ni;
        float vr = fmaf(qr, ur, fmaf(-qi, ui, fmaf(hre, pwr, -him * pwi)));
        float vi = fmaf(qr, ui, fmaf(qi, ur, fmaf(hre, pwi, him * pwr)));
        outr[(size_t)t * D] = vr;
        if (MODE == 0) {
            outr2[(size_t)t * D] = vr;
        } else {
            v2f vc; vc.x = vr; vc.y = vi;
            *(v2f*)(outc + (size_t)t * D * 2) = vc;
        }
        float tr = fmaf(pwr, ph.x, -pwi * ph.y);
        float ti = fmaf(pwr, ph.y, pwi * ph.x);
        pwr = tr; pwi = ti;
    }
}

extern "C" void kernel_launch(void* const* d_in, const int* in_sizes, int n_in,
                              void* d_out, int out_size, void* d_ws, size_t ws_size,
                              hipStream_t stream) {
    const float* x = (const float*)d_in[0];
    const float* hreal = (const float*)d_in[1];
    const float* himag = (const float*)d_in[2];
    const float* pinit = (const float*)d_in[3];
    const float* pparam = (const float*)d_in[4];
    float* le = (float*)d_ws;
    float* out = (float*)d_out;

    const int mode = (out_size >= (int)(3 * BLD)) ? 1 : 0;
    const bool fast = ws_size >= (size_t)WS_FLOATS * sizeof(float);

    if (fast) {
        int n = B * CK * D;                       // 262144 threads -> 4 waves/SIMD
        pass1_k<<<n / 256, 256, 0, stream>>>(x, pparam, le);
        if (mode == 0)
            pass2_k<0><<<n / 256, 256, 0, stream>>>(x, hreal, himag, pinit, pparam, le, out);
        else
            pass2_k<1><<<n / 256, 256, 0, stream>>>(x, hreal, himag, pinit, pparam, le, out);
    } else {
        int n = B * D;                            // 4096 threads
        if (mode == 0)
            fallback_k<0><<<(n + 255) / 256, 256, 0, stream>>>(x, hreal, himag, pinit, pparam, out);
        else
            fallback_k<1><<<(n + 255) / 256, 256, 0, stream>>>(x, hreal, himag, pinit, pparam, out);
    }
}